// Round 1
// baseline (802.571 us; speedup 1.0000x reference)
//
#include <hip/hip_runtime.h>
#include <cmath>

// ---------------- problem constants ----------------
#define TOKENS 256      // B*S = 2*128
#define DD     512
#define NPAIR  2048     // TOKENS * TOPK
#define TOPK_N 8
#define MAXH   2560
#define NEXP   16

// ---------------- GEMM tile config ----------------
#define BM 64
#define BN 64
#define BK 16
#define LSTR 68   // padded LDS row stride (floats); 68*4B keeps float4 alignment, breaks bank conflicts

// ---------------- workspace layout (float offsets) ----------------
static const long OFF_H1      = 0;                               // 256*512
static const long OFF_H2      = OFF_H1 + 256L*512;               // 256*256
static const long OFF_SCORES  = OFF_H2 + 256L*256;               // 256*4096
static const long OFF_PRE     = OFF_SCORES + 256L*4096;          // 16*256*512 (lin, then act(LN) in place)
static const long OFF_Y       = OFF_PRE + 16L*256*512;           // 2048*2560 hidden
static const long OFF_MLPOUT  = OFF_Y + 2048L*2560;              // 2048*512
static const long OFF_POSTLIN = OFF_MLPOUT + 2048L*512;          // 2048*512
static const long OFF_W       = OFF_POSTLIN + 2048L*512;         // 2048
static const long OFF_INT     = OFF_W + 2048;                    // int region below
// int offsets (within int region)
static const int I_PRE      = 0;      // 2048
static const int I_MLP      = 2048;   // 2048
static const int I_POST     = 4096;   // 2048
static const int I_MLPLIST  = 6144;   // 2048
static const int I_POSTLIST = 8192;   // 2048
static const int I_OFFM     = 10240;  // 17 (padded 32)
static const int I_OFFP     = 10272;  // 17

// ---------------- activations ----------------
__device__ __forceinline__ float act_apply(int a, float v){
  switch (a){
    case 0:  return 0.5f * v * (1.0f + erff(v * 0.7071067811865476f)); // exact gelu
    case 1:  return fmaxf(v, 0.0f);                                     // relu
    case 2:  return tanhf(v);                                           // tanh
    case 3:  return v / (1.0f + expf(-v));                              // silu
    default: return v;
  }
}

// ---------------- shared fp32 GEMM core: 64x64 tile, BK=16, 256 thr, 4x4/thread ----------------
__device__ __forceinline__ void gemm_core(
    const float* __restrict__ arow,        // this thread's A row (k=0), nullptr -> zeros
    const float* __restrict__ Bt,          // &B[0][n0]
    int ldb, int K,
    float (&acc)[4][4], float* As, float* Bs)
{
  const int tid = threadIdx.x;
  const int kq  = tid & 3;          // A k-quad
  const int bn  = (tid & 15) << 2;  // B col in tile
  const int bk  = tid >> 4;         // B k-row in tile
  const int tx  = tid & 15;
  const int ty  = tid >> 4;
  const int am  = tid >> 2;         // A row in tile (fixed per thread)

  for (int k0 = 0; k0 < K; k0 += BK){
    float4 av = make_float4(0.f,0.f,0.f,0.f);
    if (arow) av = *reinterpret_cast<const float4*>(arow + k0 + (kq<<2));
    float4 bv = *reinterpret_cast<const float4*>(Bt + (long)(k0+bk)*ldb + bn);
    __syncthreads();  // protect previous iteration's LDS reads
    As[(kq*4+0)*LSTR + am] = av.x;
    As[(kq*4+1)*LSTR + am] = av.y;
    As[(kq*4+2)*LSTR + am] = av.z;
    As[(kq*4+3)*LSTR + am] = av.w;
    *reinterpret_cast<float4*>(Bs + bk*LSTR + bn) = bv;
    __syncthreads();
#pragma unroll
    for (int kk = 0; kk < BK; ++kk){
      float4 a = *reinterpret_cast<const float4*>(As + kk*LSTR + (ty<<2));
      float4 b = *reinterpret_cast<const float4*>(Bs + kk*LSTR + (tx<<2));
      acc[0][0]=fmaf(a.x,b.x,acc[0][0]); acc[0][1]=fmaf(a.x,b.y,acc[0][1]);
      acc[0][2]=fmaf(a.x,b.z,acc[0][2]); acc[0][3]=fmaf(a.x,b.w,acc[0][3]);
      acc[1][0]=fmaf(a.y,b.x,acc[1][0]); acc[1][1]=fmaf(a.y,b.y,acc[1][1]);
      acc[1][2]=fmaf(a.y,b.z,acc[1][2]); acc[1][3]=fmaf(a.y,b.w,acc[1][3]);
      acc[2][0]=fmaf(a.z,b.x,acc[2][0]); acc[2][1]=fmaf(a.z,b.y,acc[2][1]);
      acc[2][2]=fmaf(a.z,b.z,acc[2][2]); acc[2][3]=fmaf(a.z,b.w,acc[2][3]);
      acc[3][0]=fmaf(a.w,b.x,acc[3][0]); acc[3][1]=fmaf(a.w,b.y,acc[3][1]);
      acc[3][2]=fmaf(a.w,b.z,acc[3][2]); acc[3][3]=fmaf(a.w,b.w,acc[3][3]);
    }
  }
}

// ---------------- dense GEMM + bias + act (router & pre), optional batch z ----------------
__global__ __launch_bounds__(256) void gemm_bias_act_kernel(
    const float* __restrict__ A, int lda, long sAz,
    const float* __restrict__ B, int ldb, long sBz,
    const float* __restrict__ bias, long sbz,
    float* __restrict__ C, int ldc, long sCz,
    int K, int act)
{
  __shared__ float As[BK*LSTR];
  __shared__ float Bs[BK*LSTR];
  const int n0   = blockIdx.x * BN;
  const int row0 = blockIdx.y * BM;
  const int z    = blockIdx.z;
  const float* Ab = A + (long)z*sAz;
  const float* Bt = B + (long)z*sBz + n0;
  const float* bb = bias + (long)z*sbz + n0;
  float* Cb = C + (long)z*sCz;
  const int tid = threadIdx.x;
  const int am = tid >> 2;
  const float* arow = Ab + (long)(row0 + am)*lda;
  float acc[4][4] = {};
  gemm_core(arow, Bt, ldb, K, acc, As, Bs);
  const int tx = tid & 15, ty = tid >> 4;
#pragma unroll
  for (int i = 0; i < 4; ++i){
    const int r = row0 + ty*4 + i;
    float4 o;
    o.x = act_apply(act, acc[i][0] + bb[tx*4+0]);
    o.y = act_apply(act, acc[i][1] + bb[tx*4+1]);
    o.z = act_apply(act, acc[i][2] + bb[tx*4+2]);
    o.w = act_apply(act, acc[i][3] + bb[tx*4+3]);
    *reinterpret_cast<float4*>(Cb + (long)r*ldc + n0 + tx*4) = o;
  }
}

// ---------------- softmax + top-8 per token ----------------
__global__ __launch_bounds__(256) void router_topk_kernel(
    const float* __restrict__ scores, const float* __restrict__ temp,
    float* __restrict__ w_arr, int* __restrict__ pre_arr,
    int* __restrict__ mlp_arr, int* __restrict__ post_arr)
{
  const int t = blockIdx.x, tid = threadIdx.x;
  const float invT = 1.0f / temp[0];
  float q[16];
#pragma unroll
  for (int j = 0; j < 16; ++j) q[j] = scores[(long)t*4096 + tid + (j<<8)] * invT;

  __shared__ float rv[256];
  __shared__ int   ri[256];
  // max
  float lm = -INFINITY;
#pragma unroll
  for (int j = 0; j < 16; ++j) lm = fmaxf(lm, q[j]);
  rv[tid] = lm; __syncthreads();
  for (int off = 128; off > 0; off >>= 1){
    if (tid < off) rv[tid] = fmaxf(rv[tid], rv[tid+off]);
    __syncthreads();
  }
  const float qmax = rv[0]; __syncthreads();
  // denom
  float ls = 0.f;
#pragma unroll
  for (int j = 0; j < 16; ++j) ls += expf(q[j] - qmax);
  rv[tid] = ls; __syncthreads();
  for (int off = 128; off > 0; off >>= 1){
    if (tid < off) rv[tid] += rv[tid+off];
    __syncthreads();
  }
  const float denom = rv[0]; __syncthreads();
  // iterative top-8 (argmax + mask)
  __shared__ float topv[8];
  __shared__ int   topi[8];
  float v[16];
#pragma unroll
  for (int j = 0; j < 16; ++j) v[j] = q[j];
  for (int r = 0; r < 8; ++r){
    float lb = -INFINITY; int li = 0x7fffffff;
#pragma unroll
    for (int j = 0; j < 16; ++j){
      int gi = tid + (j<<8);
      if (v[j] > lb || (v[j] == lb && gi < li)){ lb = v[j]; li = gi; }
    }
    rv[tid] = lb; ri[tid] = li; __syncthreads();
    for (int off = 128; off > 0; off >>= 1){
      if (tid < off){
        if (rv[tid+off] > rv[tid] || (rv[tid+off] == rv[tid] && ri[tid+off] < ri[tid])){
          rv[tid] = rv[tid+off]; ri[tid] = ri[tid+off];
        }
      }
      __syncthreads();
    }
    if (tid == 0){ topv[r] = rv[0]; topi[r] = ri[0]; }
    __syncthreads();
    const int win = topi[r];
    if ((win & 255) == tid) v[win >> 8] = -INFINITY;
    __syncthreads();
  }
  if (tid < 8){
    const int idx = topi[tid];
    const float prob = expf(topv[tid] - qmax) / denom;
    const float wgt = (prob >= 1e-6f) ? prob : 0.0f;
    const int p = t*TOPK_N + tid;
    w_arr[p]    = wgt;
    pre_arr[p]  = idx >> 8;
    mlp_arr[p]  = (idx >> 4) & 15;
    post_arr[p] = idx & 15;
  }
}

// ---------------- bucket build: per-expert sorted pair lists ----------------
__global__ __launch_bounds__(256) void bucket_kernel(
    const int* __restrict__ mlp_arr, const int* __restrict__ post_arr,
    int* __restrict__ mlp_list, int* __restrict__ post_list,
    int* __restrict__ off_m, int* __restrict__ off_p)
{
  __shared__ int cm[16], cp[16], om[17], op[17];
  const int tid = threadIdx.x;
  if (tid < 16){ cm[tid] = 0; cp[tid] = 0; }
  __syncthreads();
  for (int p = tid; p < NPAIR; p += 256){
    atomicAdd(&cm[mlp_arr[p]], 1);
    atomicAdd(&cp[post_arr[p]], 1);
  }
  __syncthreads();
  if (tid == 0){
    int am = 0, ap = 0;
    for (int e = 0; e < 16; ++e){ om[e] = am; am += cm[e]; op[e] = ap; ap += cp[e]; }
    om[16] = am; op[16] = ap;
  }
  __syncthreads();
  if (tid < 17){ off_m[tid] = om[tid]; off_p[tid] = op[tid]; }
  if (tid < 16){ cm[tid] = om[tid]; cp[tid] = op[tid]; }
  __syncthreads();
  for (int p = tid; p < NPAIR; p += 256){
    const int pm = atomicAdd(&cm[mlp_arr[p]], 1);  mlp_list[pm]  = p;
    const int pp = atomicAdd(&cp[post_arr[p]], 1); post_list[pp] = p;
  }
}

// ---------------- LN + act over pre_lin rows (in place) ----------------
__global__ __launch_bounds__(256) void ln_act_pre_kernel(
    float* __restrict__ buf, const float* __restrict__ g, const float* __restrict__ be)
{
  const int bid = blockIdx.x;        // e*256 + t
  const int e = bid >> 8;
  const int tid = threadIdx.x;
  float* row = buf + (long)bid * DD;
  const float x1 = row[tid], x2 = row[tid+256];
  __shared__ float s1[256], s2[256];
  s1[tid] = x1 + x2; s2[tid] = x1*x1 + x2*x2;
  __syncthreads();
  for (int off = 128; off > 0; off >>= 1){
    if (tid < off){ s1[tid] += s1[tid+off]; s2[tid] += s2[tid+off]; }
    __syncthreads();
  }
  const float mu  = s1[0] * (1.0f/512.0f);
  const float var = s2[0] * (1.0f/512.0f) - mu*mu;
  const float inv = 1.0f / sqrtf(var + 1e-5f);
  const int a = e & 3;
  const float y1 = (x1 - mu) * inv * g[e*DD + tid]       + be[e*DD + tid];
  const float y2 = (x2 - mu) * inv * g[e*DD + tid + 256] + be[e*DD + tid + 256];
  row[tid]     = act_apply(a, y1);
  row[tid+256] = act_apply(a, y2);
}

// ---------------- grouped GEMM 1: xin(sel pre rows) @ w1[e][:, :he] + b1, act ----------------
__global__ __launch_bounds__(256) void gemm_mlp1_kernel(
    const float* __restrict__ pre_act,  // [16][256][512] activated
    const float* __restrict__ w1, const float* __restrict__ b1,
    const int* __restrict__ mlp_list, const int* __restrict__ off_m,
    const int* __restrict__ pre_arr, float* __restrict__ y)
{
  const int e = blockIdx.z;
  const int base = off_m[e];
  const int cnt  = off_m[e+1] - base;
  const int he   = 512 * (2 + (e >> 2));
  const int n0   = blockIdx.x * BN;
  const int row0 = blockIdx.y * BM;
  if (row0 >= cnt || n0 >= he) return;
  __shared__ float As[BK*LSTR];
  __shared__ float Bs[BK*LSTR];
  const int tid = threadIdx.x;
  const int am = tid >> 2;
  const float* arow = nullptr;
  const int s = row0 + am;
  if (s < cnt){
    const int p  = mlp_list[base + s];
    const int t  = p >> 3;
    const int pe = pre_arr[p];
    arow = pre_act + ((long)(pe << 8) + t) * DD;
  }
  const float* Bt = w1 + (long)e*DD*MAXH + n0;
  float acc[4][4] = {};
  gemm_core(arow, Bt, MAXH, DD, acc, As, Bs);
  const int tx = tid & 15, ty = tid >> 4;
  const int act = e & 3;
  const float* bb = b1 + e*MAXH + n0;
#pragma unroll
  for (int i = 0; i < 4; ++i){
    const int r = row0 + ty*4 + i;
    if (r < cnt){
      float4 o;
      o.x = act_apply(act, acc[i][0] + bb[tx*4+0]);
      o.y = act_apply(act, acc[i][1] + bb[tx*4+1]);
      o.z = act_apply(act, acc[i][2] + bb[tx*4+2]);
      o.w = act_apply(act, acc[i][3] + bb[tx*4+3]);
      *reinterpret_cast<float4*>(y + (long)(base + r)*MAXH + n0 + tx*4) = o;
    }
  }
}

// ---------------- grouped GEMM 2: y @ w2[e][:he,:] + b2 -> mlp_out[pair] ----------------
__global__ __launch_bounds__(256) void gemm_mlp2_kernel(
    const float* __restrict__ y,
    const float* __restrict__ w2, const float* __restrict__ b2,
    const int* __restrict__ mlp_list, const int* __restrict__ off_m,
    float* __restrict__ mlp_out)
{
  const int e = blockIdx.z;
  const int base = off_m[e];
  const int cnt  = off_m[e+1] - base;
  const int he   = 512 * (2 + (e >> 2));
  const int n0   = blockIdx.x * BN;
  const int row0 = blockIdx.y * BM;
  if (row0 >= cnt) return;
  __shared__ float As[BK*LSTR];
  __shared__ float Bs[BK*LSTR];
  const int tid = threadIdx.x;
  const int am = tid >> 2;
  const float* arow = nullptr;
  const int s = row0 + am;
  if (s < cnt) arow = y + (long)(base + s)*MAXH;
  const float* Bt = w2 + (long)e*MAXH*DD + n0;
  float acc[4][4] = {};
  gemm_core(arow, Bt, DD, he, acc, As, Bs);
  const int tx = tid & 15, ty = tid >> 4;
  const float* bb = b2 + e*DD + n0;
#pragma unroll
  for (int i = 0; i < 4; ++i){
    const int r = row0 + ty*4 + i;
    if (r < cnt){
      const int p = mlp_list[base + r];
      float4 o;
      o.x = acc[i][0] + bb[tx*4+0];
      o.y = acc[i][1] + bb[tx*4+1];
      o.z = acc[i][2] + bb[tx*4+2];
      o.w = acc[i][3] + bb[tx*4+3];
      *reinterpret_cast<float4*>(mlp_out + (long)p*DD + n0 + tx*4) = o;
    }
  }
}

// ---------------- grouped GEMM 3: mlp_out @ post_w[e] + post_b -> post_lin[pair] ----------------
__global__ __launch_bounds__(256) void gemm_post_kernel(
    const float* __restrict__ mlp_out,
    const float* __restrict__ pw, const float* __restrict__ pb,
    const int* __restrict__ post_list, const int* __restrict__ off_p,
    float* __restrict__ post_lin)
{
  const int e = blockIdx.z;
  const int base = off_p[e];
  const int cnt  = off_p[e+1] - base;
  const int n0   = blockIdx.x * BN;
  const int row0 = blockIdx.y * BM;
  if (row0 >= cnt) return;
  __shared__ float As[BK*LSTR];
  __shared__ float Bs[BK*LSTR];
  const int tid = threadIdx.x;
  const int am = tid >> 2;
  const float* arow = nullptr;
  const int s = row0 + am;
  if (s < cnt){
    const int p = post_list[base + s];
    arow = mlp_out + (long)p*DD;
  }
  const float* Bt = pw + (long)e*DD*DD + n0;
  float acc[4][4] = {};
  gemm_core(arow, Bt, DD, DD, acc, As, Bs);
  const int tx = tid & 15, ty = tid >> 4;
  const float* bb = pb + e*DD + n0;
#pragma unroll
  for (int i = 0; i < 4; ++i){
    const int r = row0 + ty*4 + i;
    if (r < cnt){
      const int p = post_list[base + r];
      float4 o;
      o.x = acc[i][0] + bb[tx*4+0];
      o.y = acc[i][1] + bb[tx*4+1];
      o.z = acc[i][2] + bb[tx*4+2];
      o.w = acc[i][3] + bb[tx*4+3];
      *reinterpret_cast<float4*>(post_lin + (long)p*DD + n0 + tx*4) = o;
    }
  }
}

// ---------------- final: per token, optional LN per pair + weighted sum ----------------
__global__ __launch_bounds__(256) void final_kernel(
    const float* __restrict__ post_lin, const float* __restrict__ w_arr,
    const int* __restrict__ post_arr,
    const float* __restrict__ pg, const float* __restrict__ pbe,
    float* __restrict__ out)
{
  const int t = blockIdx.x, tid = threadIdx.x;
  float a1 = 0.f, a2 = 0.f;
  __shared__ float s1[256], s2[256];
  for (int k = 0; k < TOPK_N; ++k){
    const int p = t*TOPK_N + k;
    const float wgt = w_arr[p];      // uniform across block
    if (wgt == 0.0f) continue;
    const float* row = post_lin + (long)p*DD;
    float z1 = row[tid], z2 = row[tid+256];
    const int e = post_arr[p];
    if ((e & 1) == 0){
      s1[tid] = z1 + z2; s2[tid] = z1*z1 + z2*z2;
      __syncthreads();
      for (int off = 128; off > 0; off >>= 1){
        if (tid < off){ s1[tid] += s1[tid+off]; s2[tid] += s2[tid+off]; }
        __syncthreads();
      }
      const float mu  = s1[0] * (1.0f/512.0f);
      const float var = s2[0] * (1.0f/512.0f) - mu*mu;
      const float inv = 1.0f / sqrtf(var + 1e-5f);
      z1 = (z1 - mu)*inv*pg[e*DD + tid]       + pbe[e*DD + tid];
      z2 = (z2 - mu)*inv*pg[e*DD + tid + 256] + pbe[e*DD + tid + 256];
      __syncthreads();  // protect s1/s2 reuse next iteration
    }
    a1 = fmaf(wgt, z1, a1);
    a2 = fmaf(wgt, z2, a2);
  }
  out[(long)t*DD + tid]       = a1;
  out[(long)t*DD + tid + 256] = a2;
}

// ---------------- host launch ----------------
extern "C" void kernel_launch(void* const* d_in, const int* in_sizes, int n_in,
                              void* d_out, int out_size, void* d_ws, size_t ws_size,
                              hipStream_t stream)
{
  const float* x     = (const float*)d_in[0];
  const float* r_w1  = (const float*)d_in[1];
  const float* r_b1  = (const float*)d_in[2];
  const float* r_w2  = (const float*)d_in[3];
  const float* r_b2  = (const float*)d_in[4];
  const float* r_w3  = (const float*)d_in[5];
  const float* r_b3  = (const float*)d_in[6];
  const float* temp  = (const float*)d_in[7];
  const float* pre_w = (const float*)d_in[8];
  const float* pre_b = (const float*)d_in[9];
  const float* pre_g = (const float*)d_in[10];
  const float* pre_be= (const float*)d_in[11];
  const float* mlp_w1= (const float*)d_in[12];
  const float* mlp_b1= (const float*)d_in[13];
  const float* mlp_w2= (const float*)d_in[14];
  const float* mlp_b2= (const float*)d_in[15];
  const float* post_w= (const float*)d_in[16];
  const float* post_b= (const float*)d_in[17];
  const float* post_g= (const float*)d_in[18];
  const float* post_be=(const float*)d_in[19];

  float* ws = (float*)d_ws;
  float* h1      = ws + OFF_H1;
  float* h2      = ws + OFF_H2;
  float* scores  = ws + OFF_SCORES;
  float* pre_lin = ws + OFF_PRE;
  float* ybuf    = ws + OFF_Y;
  float* mlp_out = ws + OFF_MLPOUT;
  float* post_lin= ws + OFF_POSTLIN;
  float* w_arr   = ws + OFF_W;
  int*   wsi     = (int*)(ws + OFF_INT);
  int* pre_arr   = wsi + I_PRE;
  int* mlp_arr   = wsi + I_MLP;
  int* post_arr  = wsi + I_POST;
  int* mlp_list  = wsi + I_MLPLIST;
  int* post_list = wsi + I_POSTLIST;
  int* off_m     = wsi + I_OFFM;
  int* off_p     = wsi + I_OFFP;

  const dim3 blk(256);

  // router: h1 = gelu(x @ r_w1 + b1)   [256,512]x[512,512]
  gemm_bias_act_kernel<<<dim3(8,4,1), blk, 0, stream>>>(
      x, DD, 0, r_w1, DD, 0, r_b1, 0, h1, DD, 0, DD, 0);
  // h2 = gelu(h1 @ r_w2 + b2)          [256,512]x[512,256]
  gemm_bias_act_kernel<<<dim3(4,4,1), blk, 0, stream>>>(
      h1, DD, 0, r_w2, 256, 0, r_b2, 0, h2, 256, 0, DD, 0);
  // scores = h2 @ r_w3 + b3            [256,256]x[256,4096]
  gemm_bias_act_kernel<<<dim3(64,4,1), blk, 0, stream>>>(
      h2, 256, 0, r_w3, 4096, 0, r_b3, 0, scores, 4096, 0, 256, -1);
  // softmax + top-8
  router_topk_kernel<<<dim3(TOKENS), blk, 0, stream>>>(
      scores, temp, w_arr, pre_arr, mlp_arr, post_arr);
  // bucket build
  bucket_kernel<<<dim3(1), blk, 0, stream>>>(
      mlp_arr, post_arr, mlp_list, post_list, off_m, off_p);
  // pre experts (dense, batched over e): pre_lin = x @ pre_w[e] + pre_b[e]
  gemm_bias_act_kernel<<<dim3(8,4,16), blk, 0, stream>>>(
      x, DD, 0, pre_w, DD, (long)DD*DD, pre_b, DD, pre_lin, DD, (long)TOKENS*DD, DD, -1);
  // LN + act per (e,t) row, in place
  ln_act_pre_kernel<<<dim3(16*TOKENS), blk, 0, stream>>>(pre_lin, pre_g, pre_be);
  // grouped mlp1: y = act(xin @ w1[:, :he] + b1)
  gemm_mlp1_kernel<<<dim3(40,32,16), blk, 0, stream>>>(
      pre_lin, mlp_w1, mlp_b1, mlp_list, off_m, pre_arr, ybuf);
  // grouped mlp2: mlp_out = y @ w2[:he,:] + b2
  gemm_mlp2_kernel<<<dim3(8,32,16), blk, 0, stream>>>(
      ybuf, mlp_w2, mlp_b2, mlp_list, off_m, mlp_out);
  // grouped post: post_lin = mlp_out @ post_w + post_b
  gemm_post_kernel<<<dim3(8,32,16), blk, 0, stream>>>(
      mlp_out, post_w, post_b, post_list, off_p, post_lin);
  // final: LN (even experts) + weighted sum -> out
  final_kernel<<<dim3(TOKENS), blk, 0, stream>>>(
      post_lin, w_arr, post_arr, post_g, post_be, (float*)d_out);

  (void)in_sizes; (void)n_in; (void)out_size; (void)ws_size;
}

// Round 4
// 739.192 us; speedup vs baseline: 1.0857x; 1.0857x over previous
//
#include <hip/hip_runtime.h>
#include <cmath>

// ---------------- problem constants ----------------
#define TOKENS 256      // B*S = 2*128
#define DD     512
#define NPAIR  2048     // TOKENS * TOPK
#define TOPK_N 8
#define MAXH   2560
#define NEXP   16

// ---------------- GEMM tile config ----------------
#define BM 64
#define BN 64
#define BK 16
#define LSTR 68   // padded LDS row stride (floats)

// ---------------- workspace layout (float offsets) ----------------
static const long OFF_H1      = 0;                               // 256*512
static const long OFF_H2      = OFF_H1 + 256L*512;               // 256*256
static const long OFF_SCORES  = OFF_H2 + 256L*256;               // 256*4096
static const long OFF_PRE     = OFF_SCORES + 256L*4096;          // 16*256*512
static const long OFF_Y       = OFF_PRE + 16L*256*512;           // 2048*2560
static const long OFF_MLPOUT  = OFF_Y + 2048L*2560;              // 2048*512
static const long OFF_POSTLIN = OFF_MLPOUT + 2048L*512;          // 2048*512
static const long OFF_W       = OFF_POSTLIN + 2048L*512;         // 2048
static const long OFF_INT     = OFF_W + 2048;                    // int region below
static const int I_PRE      = 0;      // 2048
static const int I_MLP      = 2048;   // 2048
static const int I_POST     = 4096;   // 2048
static const int I_MLPLIST  = 6144;   // 2048
static const int I_POSTLIST = 8192;   // 2048
static const int I_OFFM     = 10240;  // 17 (padded 32)
static const int I_OFFP     = 10272;  // 17

// ---------------- activations ----------------
__device__ __forceinline__ float act_apply(int a, float v){
  switch (a){
    case 0:  return 0.5f * v * (1.0f + erff(v * 0.7071067811865476f)); // exact gelu
    case 1:  return fmaxf(v, 0.0f);
    case 2:  return tanhf(v);
    case 3:  return v / (1.0f + expf(-v));
    default: return v;
  }
}

// ---------------- fp32 GEMM core: 64x64 tile, K-chunk, 256 thr, 4x4/thread ----------------
__device__ __forceinline__ void gemm_core(
    const float* __restrict__ arow,        // this thread's A row, advanced to k-chunk start; nullptr -> zeros
    const float* __restrict__ Bt,          // &B[k_begin][n0]
    int ldb, int K,                        // K = chunk length (multiple of BK)
    float (&acc)[4][4], float* As, float* Bs)
{
  const int tid = threadIdx.x;
  const int kq  = tid & 3;          // A k-quad
  const int bn  = (tid & 15) << 2;  // B col in tile
  const int bk  = tid >> 4;         // B k-row in tile
  const int tx  = tid & 15;
  const int ty  = tid >> 4;
  const int am  = tid >> 2;         // A row in tile

  for (int k0 = 0; k0 < K; k0 += BK){
    float4 av = make_float4(0.f,0.f,0.f,0.f);
    if (arow) av = *reinterpret_cast<const float4*>(arow + k0 + (kq<<2));
    float4 bv = *reinterpret_cast<const float4*>(Bt + (long)(k0+bk)*ldb + bn);
    __syncthreads();
    As[(kq*4+0)*LSTR + am] = av.x;
    As[(kq*4+1)*LSTR + am] = av.y;
    As[(kq*4+2)*LSTR + am] = av.z;
    As[(kq*4+3)*LSTR + am] = av.w;
    *reinterpret_cast<float4*>(Bs + bk*LSTR + bn) = bv;
    __syncthreads();
#pragma unroll
    for (int kk = 0; kk < BK; ++kk){
      float4 a = *reinterpret_cast<const float4*>(As + kk*LSTR + (ty<<2));
      float4 b = *reinterpret_cast<const float4*>(Bs + kk*LSTR + (tx<<2));
      acc[0][0]=fmaf(a.x,b.x,acc[0][0]); acc[0][1]=fmaf(a.x,b.y,acc[0][1]);
      acc[0][2]=fmaf(a.x,b.z,acc[0][2]); acc[0][3]=fmaf(a.x,b.w,acc[0][3]);
      acc[1][0]=fmaf(a.y,b.x,acc[1][0]); acc[1][1]=fmaf(a.y,b.y,acc[1][1]);
      acc[1][2]=fmaf(a.y,b.z,acc[1][2]); acc[1][3]=fmaf(a.y,b.w,acc[1][3]);
      acc[2][0]=fmaf(a.z,b.x,acc[2][0]); acc[2][1]=fmaf(a.z,b.y,acc[2][1]);
      acc[2][2]=fmaf(a.z,b.z,acc[2][2]); acc[2][3]=fmaf(a.z,b.w,acc[2][3]);
      acc[3][0]=fmaf(a.w,b.x,acc[3][0]); acc[3][1]=fmaf(a.w,b.y,acc[3][1]);
      acc[3][2]=fmaf(a.w,b.z,acc[3][2]); acc[3][3]=fmaf(a.w,b.w,acc[3][3]);
    }
  }
}

// ---------------- init: out[z][m][n] = bias[z][n]  (zsize = M*N, mult of 1024) ----------------
__global__ __launch_bounds__(256) void init_bias_kernel(
    float* __restrict__ out, const float* __restrict__ bias, int N, long zsize)
{
  const int z = blockIdx.y;
  const long idx = ((long)blockIdx.x*256 + threadIdx.x) * 4;
  if (idx >= zsize) return;
  const int n = (int)(idx % N);
  const float4 b = *reinterpret_cast<const float4*>(bias + (long)z*N + n);
  *reinterpret_cast<float4*>(out + (long)z*zsize + idx) = b;
}

// ---------------- elementwise act in place over n4total float4s ----------------
__global__ __launch_bounds__(256) void act_dense_kernel(
    float* __restrict__ buf, long n4total, int act)
{
  const long i = (long)blockIdx.x*256 + threadIdx.x;
  if (i >= n4total) return;
  float4 v = reinterpret_cast<float4*>(buf)[i];
  v.x = act_apply(act, v.x); v.y = act_apply(act, v.y);
  v.z = act_apply(act, v.z); v.w = act_apply(act, v.w);
  reinterpret_cast<float4*>(buf)[i] = v;
}

// ---------------- dense batched split-K GEMM: C[z] += A[z] @ B[z], atomic ----------------
__global__ __launch_bounds__(256) void gemm_dense_splitk_kernel(
    const float* __restrict__ A, int lda, long sAz,
    const float* __restrict__ B, int ldb, long sBz,
    float* __restrict__ C, int ldc, long sCz,
    int K, int KSPL, int nsplit)
{
  __shared__ float As[BK*LSTR];
  __shared__ float Bs[BK*LSTR];
  const int n0   = blockIdx.x * BN;
  const int row0 = (blockIdx.y / nsplit) * BM;
  const int k0   = (blockIdx.y % nsplit) * KSPL;
  const int z    = blockIdx.z;
  if (k0 >= K) return;
  const int tid = threadIdx.x;
  const int am = tid >> 2;
  const float* arow = A + (long)z*sAz + (long)(row0 + am)*lda + k0;
  const float* Bt   = B + (long)z*sBz + (long)k0*ldb + n0;
  float* Cb = C + (long)z*sCz;
  float acc[4][4] = {};
  gemm_core(arow, Bt, ldb, KSPL, acc, As, Bs);
  const int tx = tid & 15, ty = tid >> 4;
#pragma unroll
  for (int i = 0; i < 4; ++i){
    const int r = row0 + ty*4 + i;
    float* crow = Cb + (long)r*ldc + n0 + tx*4;
#pragma unroll
    for (int j = 0; j < 4; ++j) atomicAdd(crow + j, acc[i][j]);
  }
}

// ---------------- softmax + top-8 per token ----------------
__global__ __launch_bounds__(256) void router_topk_kernel(
    const float* __restrict__ scores, const float* __restrict__ temp,
    float* __restrict__ w_arr, int* __restrict__ pre_arr,
    int* __restrict__ mlp_arr, int* __restrict__ post_arr)
{
  const int t = blockIdx.x, tid = threadIdx.x;
  const float invT = 1.0f / temp[0];
  float q[16];
#pragma unroll
  for (int j = 0; j < 16; ++j) q[j] = scores[(long)t*4096 + tid + (j<<8)] * invT;

  __shared__ float rv[256];
  __shared__ int   ri[256];
  float lm = -INFINITY;
#pragma unroll
  for (int j = 0; j < 16; ++j) lm = fmaxf(lm, q[j]);
  rv[tid] = lm; __syncthreads();
  for (int off = 128; off > 0; off >>= 1){
    if (tid < off) rv[tid] = fmaxf(rv[tid], rv[tid+off]);
    __syncthreads();
  }
  const float qmax = rv[0]; __syncthreads();
  float ls = 0.f;
#pragma unroll
  for (int j = 0; j < 16; ++j) ls += expf(q[j] - qmax);
  rv[tid] = ls; __syncthreads();
  for (int off = 128; off > 0; off >>= 1){
    if (tid < off) rv[tid] += rv[tid+off];
    __syncthreads();
  }
  const float denom = rv[0]; __syncthreads();
  __shared__ float topv[8];
  __shared__ int   topi[8];
  float v[16];
#pragma unroll
  for (int j = 0; j < 16; ++j) v[j] = q[j];
  for (int r = 0; r < 8; ++r){
    float lb = -INFINITY; int li = 0x7fffffff;
#pragma unroll
    for (int j = 0; j < 16; ++j){
      int gi = tid + (j<<8);
      if (v[j] > lb || (v[j] == lb && gi < li)){ lb = v[j]; li = gi; }
    }
    rv[tid] = lb; ri[tid] = li; __syncthreads();
    for (int off = 128; off > 0; off >>= 1){
      if (tid < off){
        if (rv[tid+off] > rv[tid] || (rv[tid+off] == rv[tid] && ri[tid+off] < ri[tid])){
          rv[tid] = rv[tid+off]; ri[tid] = ri[tid+off];
        }
      }
      __syncthreads();
    }
    if (tid == 0){ topv[r] = rv[0]; topi[r] = ri[0]; }
    __syncthreads();
    const int win = topi[r];
    if ((win & 255) == tid) v[win >> 8] = -INFINITY;
    __syncthreads();
  }
  if (tid < 8){
    const int idx = topi[tid];
    const float prob = expf(topv[tid] - qmax) / denom;
    const float wgt = (prob >= 1e-6f) ? prob : 0.0f;
    const int p = t*TOPK_N + tid;
    w_arr[p]    = wgt;
    pre_arr[p]  = idx >> 8;
    mlp_arr[p]  = (idx >> 4) & 15;
    post_arr[p] = idx & 15;
  }
}

// ---------------- bucket build ----------------
__global__ __launch_bounds__(256) void bucket_kernel(
    const int* __restrict__ mlp_arr, const int* __restrict__ post_arr,
    int* __restrict__ mlp_list, int* __restrict__ post_list,
    int* __restrict__ off_m, int* __restrict__ off_p)
{
  __shared__ int cm[16], cp[16], om[17], op[17];
  const int tid = threadIdx.x;
  if (tid < 16){ cm[tid] = 0; cp[tid] = 0; }
  __syncthreads();
  for (int p = tid; p < NPAIR; p += 256){
    atomicAdd(&cm[mlp_arr[p]], 1);
    atomicAdd(&cp[post_arr[p]], 1);
  }
  __syncthreads();
  if (tid == 0){
    int am = 0, ap = 0;
    for (int e = 0; e < 16; ++e){ om[e] = am; am += cm[e]; op[e] = ap; ap += cp[e]; }
    om[16] = am; op[16] = ap;
  }
  __syncthreads();
  if (tid < 17){ off_m[tid] = om[tid]; off_p[tid] = op[tid]; }
  if (tid < 16){ cm[tid] = om[tid]; cp[tid] = op[tid]; }
  __syncthreads();
  for (int p = tid; p < NPAIR; p += 256){
    const int pm = atomicAdd(&cm[mlp_arr[p]], 1);  mlp_list[pm]  = p;
    const int pp = atomicAdd(&cp[post_arr[p]], 1); post_list[pp] = p;
  }
}

// ---------------- LN + act over pre_lin rows (in place) ----------------
__global__ __launch_bounds__(256) void ln_act_pre_kernel(
    float* __restrict__ buf, const float* __restrict__ g, const float* __restrict__ be)
{
  const int bid = blockIdx.x;        // e*256 + t
  const int e = bid >> 8;
  const int tid = threadIdx.x;
  float* row = buf + (long)bid * DD;
  const float x1 = row[tid], x2 = row[tid+256];
  __shared__ float s1[256], s2[256];
  s1[tid] = x1 + x2; s2[tid] = x1*x1 + x2*x2;
  __syncthreads();
  for (int off = 128; off > 0; off >>= 1){
    if (tid < off){ s1[tid] += s1[tid+off]; s2[tid] += s2[tid+off]; }
    __syncthreads();
  }
  const float mu  = s1[0] * (1.0f/512.0f);
  const float var = s2[0] * (1.0f/512.0f) - mu*mu;
  const float inv = 1.0f / sqrtf(var + 1e-5f);
  const int a = e & 3;
  const float y1 = (x1 - mu) * inv * g[e*DD + tid]       + be[e*DD + tid];
  const float y2 = (x2 - mu) * inv * g[e*DD + tid + 256] + be[e*DD + tid + 256];
  row[tid]     = act_apply(a, y1);
  row[tid+256] = act_apply(a, y2);
}

// ---------------- init ybuf rows with b1[e], init mlp_out/post_lin with b2/post_b ----------------
__global__ __launch_bounds__(256) void init_ybuf_kernel(
    float* __restrict__ y, const float* __restrict__ b1,
    const int* __restrict__ mlp_list, const int* __restrict__ mlp_arr)
{
  const int s = blockIdx.x;
  const int e = mlp_arr[mlp_list[s]];
  const int he4 = (512 * (2 + (e >> 2))) >> 2;
  const int tid = threadIdx.x;
  float4* dst = reinterpret_cast<float4*>(y) + (long)s*(MAXH/4);
  const float4* src = reinterpret_cast<const float4*>(b1) + (long)e*(MAXH/4);
  for (int n = tid; n < he4; n += 256) dst[n] = src[n];
}

__global__ __launch_bounds__(256) void init_pair_kernel(
    float* __restrict__ mlp_out, const float* __restrict__ b2,
    float* __restrict__ post_lin, const float* __restrict__ pb,
    const int* __restrict__ mlp_arr, const int* __restrict__ post_arr)
{
  const int p = blockIdx.x;
  const int tid = threadIdx.x;
  if (tid < 128){
    const int em = mlp_arr[p], ep = post_arr[p];
    reinterpret_cast<float4*>(mlp_out)[(long)p*128 + tid] =
        reinterpret_cast<const float4*>(b2)[(long)em*128 + tid];
    reinterpret_cast<float4*>(post_lin)[(long)p*128 + tid] =
        reinterpret_cast<const float4*>(pb)[(long)ep*128 + tid];
  }
}

// ---------------- act over ybuf rows (per-row expert act) ----------------
__global__ __launch_bounds__(256) void act_ybuf_kernel(
    float* __restrict__ y, const int* __restrict__ mlp_list, const int* __restrict__ mlp_arr)
{
  const int s = blockIdx.x;
  const int e = mlp_arr[mlp_list[s]];
  const int a = e & 3;
  const int he4 = (512 * (2 + (e >> 2))) >> 2;
  const int tid = threadIdx.x;
  float4* row = reinterpret_cast<float4*>(y) + (long)s*(MAXH/4);
  for (int n = tid; n < he4; n += 256){
    float4 v = row[n];
    v.x = act_apply(a, v.x); v.y = act_apply(a, v.y);
    v.z = act_apply(a, v.z); v.w = act_apply(a, v.w);
    row[n] = v;
  }
}

// ---------------- grouped GEMM 1 (split-K): ybuf += pre_act[sel] @ w1[:, :he] ----------------
__global__ __launch_bounds__(256) void gemm_grp1_kernel(
    const float* __restrict__ pre_act,
    const float* __restrict__ w1,
    const int* __restrict__ mlp_list, const int* __restrict__ off_m,
    const int* __restrict__ pre_arr, float* __restrict__ y,
    int KSPL, int nsplit)
{
  const int e = blockIdx.z;
  const int base = off_m[e];
  const int cnt  = off_m[e+1] - base;
  const int he   = 512 * (2 + (e >> 2));
  const int n0   = blockIdx.x * BN;
  const int row0 = (blockIdx.y / nsplit) * BM;
  const int k0   = (blockIdx.y % nsplit) * KSPL;
  if (row0 >= cnt || n0 >= he) return;
  __shared__ float As[BK*LSTR];
  __shared__ float Bs[BK*LSTR];
  const int tid = threadIdx.x;
  const int am = tid >> 2;
  const float* arow = nullptr;
  const int s = row0 + am;
  if (s < cnt){
    const int p  = mlp_list[base + s];
    const int t  = p >> 3;
    const int pe = pre_arr[p];
    arow = pre_act + ((long)(pe << 8) + t) * DD + k0;
  }
  const float* Bt = w1 + (long)e*DD*MAXH + (long)k0*MAXH + n0;
  float acc[4][4] = {};
  gemm_core(arow, Bt, MAXH, KSPL, acc, As, Bs);
  const int tx = tid & 15, ty = tid >> 4;
#pragma unroll
  for (int i = 0; i < 4; ++i){
    const int r = row0 + ty*4 + i;
    if (r < cnt){
      float* crow = y + (long)(base + r)*MAXH + n0 + tx*4;
#pragma unroll
      for (int j = 0; j < 4; ++j) atomicAdd(crow + j, acc[i][j]);
    }
  }
}

// ---------------- grouped GEMM 2 (split-K): mlp_out[p] += y @ w2[:he,:] ----------------
__global__ __launch_bounds__(256) void gemm_grp2_kernel(
    const float* __restrict__ y,
    const float* __restrict__ w2,
    const int* __restrict__ mlp_list, const int* __restrict__ off_m,
    float* __restrict__ mlp_out,
    int KSPL, int nsplit)
{
  const int e = blockIdx.z;
  const int base = off_m[e];
  const int cnt  = off_m[e+1] - base;
  const int he   = 512 * (2 + (e >> 2));
  const int n0   = blockIdx.x * BN;
  const int row0 = (blockIdx.y / nsplit) * BM;
  const int k0   = (blockIdx.y % nsplit) * KSPL;
  if (row0 >= cnt || k0 >= he) return;
  __shared__ float As[BK*LSTR];
  __shared__ float Bs[BK*LSTR];
  const int tid = threadIdx.x;
  const int am = tid >> 2;
  const float* arow = nullptr;
  const int s = row0 + am;
  if (s < cnt) arow = y + (long)(base + s)*MAXH + k0;
  const float* Bt = w2 + (long)e*MAXH*DD + (long)k0*DD + n0;
  float acc[4][4] = {};
  gemm_core(arow, Bt, DD, KSPL, acc, As, Bs);
  const int tx = tid & 15, ty = tid >> 4;
#pragma unroll
  for (int i = 0; i < 4; ++i){
    const int r = row0 + ty*4 + i;
    if (r < cnt){
      const int p = mlp_list[base + r];
      float* crow = mlp_out + (long)p*DD + n0 + tx*4;
#pragma unroll
      for (int j = 0; j < 4; ++j) atomicAdd(crow + j, acc[i][j]);
    }
  }
}

// ---------------- grouped GEMM 3 (split-K): post_lin[p] += mlp_out[p] @ post_w[e] ----------------
__global__ __launch_bounds__(256) void gemm_post_kernel(
    const float* __restrict__ mlp_out,
    const float* __restrict__ pw,
    const int* __restrict__ post_list, const int* __restrict__ off_p,
    float* __restrict__ post_lin,
    int KSPL, int nsplit)
{
  const int e = blockIdx.z;
  const int base = off_p[e];
  const int cnt  = off_p[e+1] - base;
  const int n0   = blockIdx.x * BN;
  const int row0 = (blockIdx.y / nsplit) * BM;
  const int k0   = (blockIdx.y % nsplit) * KSPL;
  if (row0 >= cnt) return;
  __shared__ float As[BK*LSTR];
  __shared__ float Bs[BK*LSTR];
  const int tid = threadIdx.x;
  const int am = tid >> 2;
  const float* arow = nullptr;
  const int s = row0 + am;
  if (s < cnt){
    const int p = post_list[base + s];
    arow = mlp_out + (long)p*DD + k0;
  }
  const float* Bt = pw + (long)e*DD*DD + (long)k0*DD + n0;
  float acc[4][4] = {};
  gemm_core(arow, Bt, DD, KSPL, acc, As, Bs);
  const int tx = tid & 15, ty = tid >> 4;
#pragma unroll
  for (int i = 0; i < 4; ++i){
    const int r = row0 + ty*4 + i;
    if (r < cnt){
      const int p = post_list[base + r];
      float* crow = post_lin + (long)p*DD + n0 + tx*4;
#pragma unroll
      for (int j = 0; j < 4; ++j) atomicAdd(crow + j, acc[i][j]);
    }
  }
}

// ---------------- final: per token, optional LN per pair + weighted sum ----------------
__global__ __launch_bounds__(256) void final_kernel(
    const float* __restrict__ post_lin, const float* __restrict__ w_arr,
    const int* __restrict__ post_arr,
    const float* __restrict__ pg, const float* __restrict__ pbe,
    float* __restrict__ out)
{
  const int t = blockIdx.x, tid = threadIdx.x;
  float a1 = 0.f, a2 = 0.f;
  __shared__ float s1[256], s2[256];
  for (int k = 0; k < TOPK_N; ++k){
    const int p = t*TOPK_N + k;
    const float wgt = w_arr[p];      // uniform across block
    if (wgt == 0.0f) continue;
    const float* row = post_lin + (long)p*DD;
    float z1 = row[tid], z2 = row[tid+256];
    const int e = post_arr[p];
    if ((e & 1) == 0){
      s1[tid] = z1 + z2; s2[tid] = z1*z1 + z2*z2;
      __syncthreads();
      for (int off = 128; off > 0; off >>= 1){
        if (tid < off){ s1[tid] += s1[tid+off]; s2[tid] += s2[tid+off]; }
        __syncthreads();
      }
      const float mu  = s1[0] * (1.0f/512.0f);
      const float var = s2[0] * (1.0f/512.0f) - mu*mu;
      const float inv = 1.0f / sqrtf(var + 1e-5f);
      z1 = (z1 - mu)*inv*pg[e*DD + tid]       + pbe[e*DD + tid];
      z2 = (z2 - mu)*inv*pg[e*DD + tid + 256] + pbe[e*DD + tid + 256];
      __syncthreads();
    }
    a1 = fmaf(wgt, z1, a1);
    a2 = fmaf(wgt, z2, a2);
  }
  out[(long)t*DD + tid]       = a1;
  out[(long)t*DD + tid + 256] = a2;
}

// ---------------- host launch ----------------
extern "C" void kernel_launch(void* const* d_in, const int* in_sizes, int n_in,
                              void* d_out, int out_size, void* d_ws, size_t ws_size,
                              hipStream_t stream)
{
  const float* x     = (const float*)d_in[0];
  const float* r_w1  = (const float*)d_in[1];
  const float* r_b1  = (const float*)d_in[2];
  const float* r_w2  = (const float*)d_in[3];
  const float* r_b2  = (const float*)d_in[4];
  const float* r_w3  = (const float*)d_in[5];
  const float* r_b3  = (const float*)d_in[6];
  const float* temp  = (const float*)d_in[7];
  const float* pre_w = (const float*)d_in[8];
  const float* pre_b = (const float*)d_in[9];
  const float* pre_g = (const float*)d_in[10];
  const float* pre_be= (const float*)d_in[11];
  const float* mlp_w1= (const float*)d_in[12];
  const float* mlp_b1= (const float*)d_in[13];
  const float* mlp_w2= (const float*)d_in[14];
  const float* mlp_b2= (const float*)d_in[15];
  const float* post_w= (const float*)d_in[16];
  const float* post_b= (const float*)d_in[17];
  const float* post_g= (const float*)d_in[18];
  const float* post_be=(const float*)d_in[19];

  float* ws = (float*)d_ws;
  float* h1      = ws + OFF_H1;
  float* h2      = ws + OFF_H2;
  float* scores  = ws + OFF_SCORES;
  float* pre_lin = ws + OFF_PRE;
  float* ybuf    = ws + OFF_Y;
  float* mlp_out = ws + OFF_MLPOUT;
  float* post_lin= ws + OFF_POSTLIN;
  float* w_arr   = ws + OFF_W;
  int*   wsi     = (int*)(ws + OFF_INT);
  int* pre_arr   = wsi + I_PRE;
  int* mlp_arr   = wsi + I_MLP;
  int* post_arr  = wsi + I_POST;
  int* mlp_list  = wsi + I_MLPLIST;
  int* post_list = wsi + I_POSTLIST;
  int* off_m     = wsi + I_OFFM;
  int* off_p     = wsi + I_OFFP;

  const dim3 blk(256);

  // ---- router ----
  // h1 = gelu(x @ r_w1 + b1): init bias, split-K x4, act
  init_bias_kernel<<<dim3(128,1), blk, 0, stream>>>(h1, r_b1, 512, 256L*512);
  gemm_dense_splitk_kernel<<<dim3(8, 4*4, 1), blk, 0, stream>>>(
      x, DD, 0, r_w1, DD, 0, h1, DD, 0, 512, 128, 4);
  act_dense_kernel<<<dim3(128), blk, 0, stream>>>(h1, 256L*512/4, 0);
  // h2 = gelu(h1 @ r_w2 + b2)
  init_bias_kernel<<<dim3(64,1), blk, 0, stream>>>(h2, r_b2, 256, 256L*256);
  gemm_dense_splitk_kernel<<<dim3(4, 4*4, 1), blk, 0, stream>>>(
      h1, DD, 0, r_w2, 256, 0, h2, 256, 0, 512, 128, 4);
  act_dense_kernel<<<dim3(64), blk, 0, stream>>>(h2, 256L*256/4, 0);
  // scores = h2 @ r_w3 + b3
  init_bias_kernel<<<dim3(1024,1), blk, 0, stream>>>(scores, r_b3, 4096, 256L*4096);
  gemm_dense_splitk_kernel<<<dim3(64, 4*2, 1), blk, 0, stream>>>(
      h2, 256, 0, r_w3, 4096, 0, scores, 4096, 0, 256, 128, 2);
  // softmax + top-8, bucket
  router_topk_kernel<<<dim3(TOKENS), blk, 0, stream>>>(
      scores, temp, w_arr, pre_arr, mlp_arr, post_arr);
  bucket_kernel<<<dim3(1), blk, 0, stream>>>(
      mlp_arr, post_arr, mlp_list, post_list, off_m, off_p);

  // ---- pre experts (dense batched): pre_lin = x @ pre_w[e] + pre_b[e], then LN+act ----
  init_bias_kernel<<<dim3(128,16), blk, 0, stream>>>(pre_lin, pre_b, 512, 256L*512);
  gemm_dense_splitk_kernel<<<dim3(8, 4*2, 16), blk, 0, stream>>>(
      x, DD, 0, pre_w, DD, (long)DD*DD, pre_lin, DD, (long)TOKENS*DD, 512, 256, 2);
  ln_act_pre_kernel<<<dim3(16*TOKENS), blk, 0, stream>>>(pre_lin, pre_g, pre_be);

  // ---- inits for routed stages ----
  init_pair_kernel<<<dim3(NPAIR), blk, 0, stream>>>(
      mlp_out, mlp_b2, post_lin, post_b, mlp_arr, post_arr);
  init_ybuf_kernel<<<dim3(NPAIR), blk, 0, stream>>>(ybuf, mlp_b1, mlp_list, mlp_arr);

  // ---- grouped mlp1: y += xin @ w1[:, :he], split-K x2, then act ----
  gemm_grp1_kernel<<<dim3(40, 4*2, 16), blk, 0, stream>>>(
      pre_lin, mlp_w1, mlp_list, off_m, pre_arr, ybuf, 256, 2);
  act_ybuf_kernel<<<dim3(NPAIR), blk, 0, stream>>>(ybuf, mlp_list, mlp_arr);

  // ---- grouped mlp2: mlp_out += y @ w2[:he,:], split-K up to 10 ----
  gemm_grp2_kernel<<<dim3(8, 4*10, 16), blk, 0, stream>>>(
      ybuf, mlp_w2, mlp_list, off_m, mlp_out, 256, 10);

  // ---- grouped post: post_lin += mlp_out @ post_w, split-K x4 ----
  gemm_post_kernel<<<dim3(8, 4*4, 16), blk, 0, stream>>>(
      mlp_out, post_w, post_list, off_p, post_lin, 128, 4);

  // ---- final ----
  final_kernel<<<dim3(TOKENS), blk, 0, stream>>>(
      post_lin, w_arr, post_arr, post_g, post_be, (float*)d_out);

  (void)in_sizes; (void)n_in; (void)out_size; (void)ws_size;
}

// Round 5
// 502.457 us; speedup vs baseline: 1.5973x; 1.4712x over previous
//
#include <hip/hip_runtime.h>
#include <cmath>

// ---------------- problem constants ----------------
#define TOKENS 256      // B*S = 2*128
#define DD     512
#define NPAIR  2048     // TOKENS * TOPK
#define TOPK_N 8
#define MAXH   2560
#define NEXP   16

// ---------------- fp32 router GEMM tile config ----------------
#define BM 64
#define BN 64
#define BK 16
#define LSTR 68   // padded LDS row stride (floats)

// ---------------- MFMA tile config ----------------
#define TM 64
#define TN 64
#define TK 32
#define APAD 40   // shorts per LDS row: 80B, 16B-aligned, ~2-way bank spread

typedef __attribute__((ext_vector_type(8))) short short8;
typedef __attribute__((ext_vector_type(4))) float f32x4;

// ---------------- workspace layout (float offsets) ----------------
static const long OFF_H1      = 0;                               // 256*512
static const long OFF_H2      = OFF_H1 + 256L*512;               // 256*256
static const long OFF_SCORES  = OFF_H2 + 256L*256;               // 256*4096
static const long OFF_PRE     = OFF_SCORES + 256L*4096;          // 16*256*512
static const long OFF_Y       = OFF_PRE + 16L*256*512;           // 2048*2560
static const long OFF_MLPOUT  = OFF_Y + 2048L*2560;              // 2048*512
static const long OFF_POSTLIN = OFF_MLPOUT + 2048L*512;          // 2048*512
static const long OFF_W       = OFF_POSTLIN + 2048L*512;         // 2048
static const long OFF_INT     = OFF_W + 2048;                    // int region below
static const int I_PRE      = 0;      // 2048
static const int I_MLP      = 2048;   // 2048
static const int I_POST     = 4096;   // 2048
static const int I_MLPLIST  = 6144;   // 2048
static const int I_POSTLIST = 8192;   // 2048
static const int I_OFFM     = 10240;  // 17 (padded 32)
static const int I_OFFP     = 10272;  // 17

// ---------------- activations ----------------
__device__ __forceinline__ float act_apply(int a, float v){
  switch (a){
    case 0:  return 0.5f * v * (1.0f + erff(v * 0.7071067811865476f)); // exact gelu
    case 1:  return fmaxf(v, 0.0f);
    case 2:  return tanhf(v);
    case 3:  return v / (1.0f + expf(-v));
    default: return v;
  }
}

// ---------------- bf16 hi/lo split (truncation; lo captures next 8 bits) ----------------
__device__ __forceinline__ void split2(float x, short &h, short &l){
  unsigned u = __float_as_uint(x);
  h = (short)(u >> 16);
  float fh = __uint_as_float(u & 0xffff0000u);
  l = (short)(__float_as_uint(x - fh) >> 16);
}

// ---------------- MFMA 64x64 tile core, 4 waves, 3-term bf16 split ----------------
// arow: per-thread A row ptr (this thread stages row tid&63), at k=0
// Bt:   B + n0 (column offset applied), row-major with leading dim ldb
__device__ __forceinline__ void mfma_tile_core(
    const float* __restrict__ arow, const float* __restrict__ Bt,
    int ldb, int K, f32x4 (&acc)[2][2],
    short (*Ah)[APAD], short (*Al)[APAD], short (*Bh)[APAD], short (*Bl)[APAD])
{
  const int tid  = threadIdx.x;
  const int rc   = tid & 63;   // staging row (A) / col (B)
  const int kq   = tid >> 6;   // k-octet 0..3
  const int lane = tid & 63;
  const int wave = tid >> 6;
  const int wm = wave & 1, wn = wave >> 1;
  const int lr = lane & 15, kg = lane >> 4;

  for (int k0 = 0; k0 < K; k0 += TK){
    // global loads: A row 8 floats (2x float4), B column-slice 8 scalars (coalesced across lanes)
    const float* ap = arow + k0 + kq*8;
    const float4 av0 = *reinterpret_cast<const float4*>(ap);
    const float4 av1 = *reinterpret_cast<const float4*>(ap + 4);
    float bv[8];
    const float* bp = Bt + (long)(k0 + kq*8)*ldb + rc;
#pragma unroll
    for (int i = 0; i < 8; ++i) bv[i] = bp[(long)i*ldb];

    __syncthreads();  // previous iteration's frag reads complete
    const float af[8] = {av0.x,av0.y,av0.z,av0.w,av1.x,av1.y,av1.z,av1.w};
    short8 ah, al, bh, bl;
#pragma unroll
    for (int i = 0; i < 8; ++i){
      short h, l;
      split2(af[i], h, l); ah[i] = h; al[i] = l;
      split2(bv[i], h, l); bh[i] = h; bl[i] = l;
    }
    *reinterpret_cast<short8*>(&Ah[rc][kq*8]) = ah;
    *reinterpret_cast<short8*>(&Al[rc][kq*8]) = al;
    *reinterpret_cast<short8*>(&Bh[rc][kq*8]) = bh;
    *reinterpret_cast<short8*>(&Bl[rc][kq*8]) = bl;
    __syncthreads();

    short8 fah[2], fal[2], fbh[2], fbl[2];
#pragma unroll
    for (int f = 0; f < 2; ++f){
      fah[f] = *reinterpret_cast<const short8*>(&Ah[wm*32 + f*16 + lr][kg*8]);
      fal[f] = *reinterpret_cast<const short8*>(&Al[wm*32 + f*16 + lr][kg*8]);
      fbh[f] = *reinterpret_cast<const short8*>(&Bh[wn*32 + f*16 + lr][kg*8]);
      fbl[f] = *reinterpret_cast<const short8*>(&Bl[wn*32 + f*16 + lr][kg*8]);
    }
#pragma unroll
    for (int fr = 0; fr < 2; ++fr)
#pragma unroll
      for (int fc = 0; fc < 2; ++fc){
        acc[fr][fc] = __builtin_amdgcn_mfma_f32_16x16x32_bf16(fah[fr], fbh[fc], acc[fr][fc], 0, 0, 0);
        acc[fr][fc] = __builtin_amdgcn_mfma_f32_16x16x32_bf16(fah[fr], fbl[fc], acc[fr][fc], 0, 0, 0);
        acc[fr][fc] = __builtin_amdgcn_mfma_f32_16x16x32_bf16(fal[fr], fbh[fc], acc[fr][fc], 0, 0, 0);
      }
  }
}

#define MFMA_ACC_INIT(acc) do { \
  f32x4 z = {0.f, 0.f, 0.f, 0.f}; \
  acc[0][0] = z; acc[0][1] = z; acc[1][0] = z; acc[1][1] = z; } while (0)

// ---------------- pre experts: pre_lin[e] = x @ pre_w[e] + pre_b[e] ----------------
__global__ __launch_bounds__(256) void mfma_pre_kernel(
    const float* __restrict__ x, const float* __restrict__ pre_w,
    const float* __restrict__ pre_b, float* __restrict__ pre_lin)
{
  __shared__ short Ah[TM][APAD], Al[TM][APAD], Bh[TN][APAD], Bl[TN][APAD];
  const int e    = blockIdx.z;
  const int n0   = blockIdx.x * TN;
  const int row0 = blockIdx.y * TM;
  const int tid  = threadIdx.x;
  const float* arow = x + (long)(row0 + (tid & 63))*DD;
  const float* Bt   = pre_w + (long)e*DD*DD + n0;
  f32x4 acc[2][2]; MFMA_ACC_INIT(acc);
  mfma_tile_core(arow, Bt, DD, DD, acc, Ah, Al, Bh, Bl);
  const int lane = tid & 63, wave = tid >> 6;
  const int wm = wave & 1, wn = wave >> 1, lr = lane & 15, kg = lane >> 4;
  float* Cb = pre_lin + (long)e*TOKENS*DD;
#pragma unroll
  for (int fr = 0; fr < 2; ++fr)
#pragma unroll
    for (int fc = 0; fc < 2; ++fc){
      const int cc = n0 + wn*32 + fc*16 + lr;
      const float b = pre_b[e*DD + cc];
#pragma unroll
      for (int r = 0; r < 4; ++r){
        const int rr = row0 + wm*32 + fr*16 + kg*4 + r;
        Cb[(long)rr*DD + cc] = acc[fr][fc][r] + b;
      }
    }
}

// ---------------- grouped mlp1: ybuf[base+s] = act_e(pre_act[sel] @ w1[e][:, :he] + b1[e]) ----------------
__global__ __launch_bounds__(256) void mfma_grp1_kernel(
    const float* __restrict__ pre_act, const float* __restrict__ w1,
    const float* __restrict__ b1, const int* __restrict__ mlp_list,
    const int* __restrict__ off_m, const int* __restrict__ pre_arr,
    float* __restrict__ y)
{
  __shared__ short Ah[TM][APAD], Al[TM][APAD], Bh[TN][APAD], Bl[TN][APAD];
  const int e    = blockIdx.z;
  const int base = off_m[e];
  const int cnt  = off_m[e+1] - base;
  const int he   = 512 * (2 + (e >> 2));
  const int n0   = blockIdx.x * TN;
  const int row0 = blockIdx.y * TM;
  if (row0 >= cnt || n0 >= he) return;
  const int tid = threadIdx.x;
  int s = row0 + (tid & 63); if (s >= cnt) s = cnt - 1;   // clamp; guarded at write
  const int p = mlp_list[base + s];
  const float* arow = pre_act + ((long)(pre_arr[p] << 8) + (p >> 3))*DD;
  const float* Bt   = w1 + (long)e*DD*MAXH + n0;
  f32x4 acc[2][2]; MFMA_ACC_INIT(acc);
  mfma_tile_core(arow, Bt, MAXH, DD, acc, Ah, Al, Bh, Bl);
  const int lane = tid & 63, wave = tid >> 6;
  const int wm = wave & 1, wn = wave >> 1, lr = lane & 15, kg = lane >> 4;
  const int act = e & 3;
#pragma unroll
  for (int fr = 0; fr < 2; ++fr)
#pragma unroll
    for (int fc = 0; fc < 2; ++fc){
      const int cc = n0 + wn*32 + fc*16 + lr;
      const float b = b1[e*MAXH + cc];
#pragma unroll
      for (int r = 0; r < 4; ++r){
        const int rloc = row0 + wm*32 + fr*16 + kg*4 + r;
        if (rloc < cnt)
          y[(long)(base + rloc)*MAXH + cc] = act_apply(act, acc[fr][fc][r] + b);
      }
    }
}

// ---------------- grouped mlp2: mlp_out[p] = ybuf @ w2[e][:he,:] + b2[e] ----------------
__global__ __launch_bounds__(256) void mfma_grp2_kernel(
    const float* __restrict__ y, const float* __restrict__ w2,
    const float* __restrict__ b2, const int* __restrict__ mlp_list,
    const int* __restrict__ off_m, float* __restrict__ mlp_out)
{
  __shared__ short Ah[TM][APAD], Al[TM][APAD], Bh[TN][APAD], Bl[TN][APAD];
  const int e    = blockIdx.z;
  const int base = off_m[e];
  const int cnt  = off_m[e+1] - base;
  const int he   = 512 * (2 + (e >> 2));
  const int n0   = blockIdx.x * TN;
  const int row0 = blockIdx.y * TM;
  if (row0 >= cnt) return;
  const int tid = threadIdx.x;
  int s = row0 + (tid & 63); if (s >= cnt) s = cnt - 1;
  const float* arow = y + (long)(base + s)*MAXH;
  const float* Bt   = w2 + (long)e*MAXH*DD + n0;
  f32x4 acc[2][2]; MFMA_ACC_INIT(acc);
  mfma_tile_core(arow, Bt, DD, he, acc, Ah, Al, Bh, Bl);
  const int lane = tid & 63, wave = tid >> 6;
  const int wm = wave & 1, wn = wave >> 1, lr = lane & 15, kg = lane >> 4;
#pragma unroll
  for (int fr = 0; fr < 2; ++fr)
#pragma unroll
    for (int fc = 0; fc < 2; ++fc){
      const int cc = n0 + wn*32 + fc*16 + lr;
      const float b = b2[e*DD + cc];
#pragma unroll
      for (int r = 0; r < 4; ++r){
        const int rloc = row0 + wm*32 + fr*16 + kg*4 + r;
        if (rloc < cnt){
          const int pp = mlp_list[base + rloc];
          mlp_out[(long)pp*DD + cc] = acc[fr][fc][r] + b;
        }
      }
    }
}

// ---------------- grouped post: post_lin[p] = mlp_out[p] @ post_w[e] + post_b[e] ----------------
__global__ __launch_bounds__(256) void mfma_post_kernel(
    const float* __restrict__ mlp_out, const float* __restrict__ pw,
    const float* __restrict__ pb, const int* __restrict__ post_list,
    const int* __restrict__ off_p, float* __restrict__ post_lin)
{
  __shared__ short Ah[TM][APAD], Al[TM][APAD], Bh[TN][APAD], Bl[TN][APAD];
  const int e    = blockIdx.z;
  const int base = off_p[e];
  const int cnt  = off_p[e+1] - base;
  const int n0   = blockIdx.x * TN;
  const int row0 = blockIdx.y * TM;
  if (row0 >= cnt) return;
  const int tid = threadIdx.x;
  int s = row0 + (tid & 63); if (s >= cnt) s = cnt - 1;
  const float* arow = mlp_out + (long)post_list[base + s]*DD;
  const float* Bt   = pw + (long)e*DD*DD + n0;
  f32x4 acc[2][2]; MFMA_ACC_INIT(acc);
  mfma_tile_core(arow, Bt, DD, DD, acc, Ah, Al, Bh, Bl);
  const int lane = tid & 63, wave = tid >> 6;
  const int wm = wave & 1, wn = wave >> 1, lr = lane & 15, kg = lane >> 4;
#pragma unroll
  for (int fr = 0; fr < 2; ++fr)
#pragma unroll
    for (int fc = 0; fc < 2; ++fc){
      const int cc = n0 + wn*32 + fc*16 + lr;
      const float b = pb[e*DD + cc];
#pragma unroll
      for (int r = 0; r < 4; ++r){
        const int rloc = row0 + wm*32 + fr*16 + kg*4 + r;
        if (rloc < cnt){
          const int pp = post_list[base + rloc];
          post_lin[(long)pp*DD + cc] = acc[fr][fc][r] + b;
        }
      }
    }
}

// ---------------- fp32 GEMM core (router only): 64x64 tile, K-chunk, 4x4/thread ----------------
__device__ __forceinline__ void gemm_core(
    const float* __restrict__ arow, const float* __restrict__ Bt,
    int ldb, int K, float (&acc)[4][4], float* As, float* Bs)
{
  const int tid = threadIdx.x;
  const int kq  = tid & 3;
  const int bn  = (tid & 15) << 2;
  const int bk  = tid >> 4;
  const int tx  = tid & 15;
  const int ty  = tid >> 4;
  const int am  = tid >> 2;

  for (int k0 = 0; k0 < K; k0 += BK){
    float4 av = make_float4(0.f,0.f,0.f,0.f);
    if (arow) av = *reinterpret_cast<const float4*>(arow + k0 + (kq<<2));
    float4 bv = *reinterpret_cast<const float4*>(Bt + (long)(k0+bk)*ldb + bn);
    __syncthreads();
    As[(kq*4+0)*LSTR + am] = av.x;
    As[(kq*4+1)*LSTR + am] = av.y;
    As[(kq*4+2)*LSTR + am] = av.z;
    As[(kq*4+3)*LSTR + am] = av.w;
    *reinterpret_cast<float4*>(Bs + bk*LSTR + bn) = bv;
    __syncthreads();
#pragma unroll
    for (int kk = 0; kk < BK; ++kk){
      float4 a = *reinterpret_cast<const float4*>(As + kk*LSTR + (ty<<2));
      float4 b = *reinterpret_cast<const float4*>(Bs + kk*LSTR + (tx<<2));
      acc[0][0]=fmaf(a.x,b.x,acc[0][0]); acc[0][1]=fmaf(a.x,b.y,acc[0][1]);
      acc[0][2]=fmaf(a.x,b.z,acc[0][2]); acc[0][3]=fmaf(a.x,b.w,acc[0][3]);
      acc[1][0]=fmaf(a.y,b.x,acc[1][0]); acc[1][1]=fmaf(a.y,b.y,acc[1][1]);
      acc[1][2]=fmaf(a.y,b.z,acc[1][2]); acc[1][3]=fmaf(a.y,b.w,acc[1][3]);
      acc[2][0]=fmaf(a.z,b.x,acc[2][0]); acc[2][1]=fmaf(a.z,b.y,acc[2][1]);
      acc[2][2]=fmaf(a.z,b.z,acc[2][2]); acc[2][3]=fmaf(a.z,b.w,acc[2][3]);
      acc[3][0]=fmaf(a.w,b.x,acc[3][0]); acc[3][1]=fmaf(a.w,b.y,acc[3][1]);
      acc[3][2]=fmaf(a.w,b.z,acc[3][2]); acc[3][3]=fmaf(a.w,b.w,acc[3][3]);
    }
  }
}

// ---------------- init: out[m][n] = bias[n] ----------------
__global__ __launch_bounds__(256) void init_bias_kernel(
    float* __restrict__ out, const float* __restrict__ bias, int N, long zsize)
{
  const long idx = ((long)blockIdx.x*256 + threadIdx.x) * 4;
  if (idx >= zsize) return;
  const int n = (int)(idx % N);
  const float4 b = *reinterpret_cast<const float4*>(bias + n);
  *reinterpret_cast<float4*>(out + idx) = b;
}

// ---------------- elementwise act in place ----------------
__global__ __launch_bounds__(256) void act_dense_kernel(
    float* __restrict__ buf, long n4total, int act)
{
  const long i = (long)blockIdx.x*256 + threadIdx.x;
  if (i >= n4total) return;
  float4 v = reinterpret_cast<float4*>(buf)[i];
  v.x = act_apply(act, v.x); v.y = act_apply(act, v.y);
  v.z = act_apply(act, v.z); v.w = act_apply(act, v.w);
  reinterpret_cast<float4*>(buf)[i] = v;
}

// ---------------- dense split-K GEMM (router): C += A @ B, atomic ----------------
__global__ __launch_bounds__(256) void gemm_dense_splitk_kernel(
    const float* __restrict__ A, int lda,
    const float* __restrict__ B, int ldb,
    float* __restrict__ C, int ldc,
    int K, int KSPL, int nsplit)
{
  __shared__ float As[BK*LSTR];
  __shared__ float Bs[BK*LSTR];
  const int n0   = blockIdx.x * BN;
  const int row0 = (blockIdx.y / nsplit) * BM;
  const int k0   = (blockIdx.y % nsplit) * KSPL;
  if (k0 >= K) return;
  const int tid = threadIdx.x;
  const int am = tid >> 2;
  const float* arow = A + (long)(row0 + am)*lda + k0;
  const float* Bt   = B + (long)k0*ldb + n0;
  float acc[4][4] = {};
  gemm_core(arow, Bt, ldb, KSPL, acc, As, Bs);
  const int tx = tid & 15, ty = tid >> 4;
#pragma unroll
  for (int i = 0; i < 4; ++i){
    const int r = row0 + ty*4 + i;
    float* crow = C + (long)r*ldc + n0 + tx*4;
#pragma unroll
    for (int j = 0; j < 4; ++j) atomicAdd(crow + j, acc[i][j]);
  }
}

// ---------------- softmax + top-8 per token ----------------
__global__ __launch_bounds__(256) void router_topk_kernel(
    const float* __restrict__ scores, const float* __restrict__ temp,
    float* __restrict__ w_arr, int* __restrict__ pre_arr,
    int* __restrict__ mlp_arr, int* __restrict__ post_arr)
{
  const int t = blockIdx.x, tid = threadIdx.x;
  const float invT = 1.0f / temp[0];
  float q[16];
#pragma unroll
  for (int j = 0; j < 16; ++j) q[j] = scores[(long)t*4096 + tid + (j<<8)] * invT;

  __shared__ float rv[256];
  __shared__ int   ri[256];
  float lm = -INFINITY;
#pragma unroll
  for (int j = 0; j < 16; ++j) lm = fmaxf(lm, q[j]);
  rv[tid] = lm; __syncthreads();
  for (int off = 128; off > 0; off >>= 1){
    if (tid < off) rv[tid] = fmaxf(rv[tid], rv[tid+off]);
    __syncthreads();
  }
  const float qmax = rv[0]; __syncthreads();
  float ls = 0.f;
#pragma unroll
  for (int j = 0; j < 16; ++j) ls += expf(q[j] - qmax);
  rv[tid] = ls; __syncthreads();
  for (int off = 128; off > 0; off >>= 1){
    if (tid < off) rv[tid] += rv[tid+off];
    __syncthreads();
  }
  const float denom = rv[0]; __syncthreads();
  __shared__ float topv[8];
  __shared__ int   topi[8];
  float v[16];
#pragma unroll
  for (int j = 0; j < 16; ++j) v[j] = q[j];
  for (int r = 0; r < 8; ++r){
    float lb = -INFINITY; int li = 0x7fffffff;
#pragma unroll
    for (int j = 0; j < 16; ++j){
      int gi = tid + (j<<8);
      if (v[j] > lb || (v[j] == lb && gi < li)){ lb = v[j]; li = gi; }
    }
    rv[tid] = lb; ri[tid] = li; __syncthreads();
    for (int off = 128; off > 0; off >>= 1){
      if (tid < off){
        if (rv[tid+off] > rv[tid] || (rv[tid+off] == rv[tid] && ri[tid+off] < ri[tid])){
          rv[tid] = rv[tid+off]; ri[tid] = ri[tid+off];
        }
      }
      __syncthreads();
    }
    if (tid == 0){ topv[r] = rv[0]; topi[r] = ri[0]; }
    __syncthreads();
    const int win = topi[r];
    if ((win & 255) == tid) v[win >> 8] = -INFINITY;
    __syncthreads();
  }
  if (tid < 8){
    const int idx = topi[tid];
    const float prob = expf(topv[tid] - qmax) / denom;
    const float wgt = (prob >= 1e-6f) ? prob : 0.0f;
    const int p = t*TOPK_N + tid;
    w_arr[p]    = wgt;
    pre_arr[p]  = idx >> 8;
    mlp_arr[p]  = (idx >> 4) & 15;
    post_arr[p] = idx & 15;
  }
}

// ---------------- bucket build ----------------
__global__ __launch_bounds__(256) void bucket_kernel(
    const int* __restrict__ mlp_arr, const int* __restrict__ post_arr,
    int* __restrict__ mlp_list, int* __restrict__ post_list,
    int* __restrict__ off_m, int* __restrict__ off_p)
{
  __shared__ int cm[16], cp[16], om[17], op[17];
  const int tid = threadIdx.x;
  if (tid < 16){ cm[tid] = 0; cp[tid] = 0; }
  __syncthreads();
  for (int p = tid; p < NPAIR; p += 256){
    atomicAdd(&cm[mlp_arr[p]], 1);
    atomicAdd(&cp[post_arr[p]], 1);
  }
  __syncthreads();
  if (tid == 0){
    int am = 0, ap = 0;
    for (int e = 0; e < 16; ++e){ om[e] = am; am += cm[e]; op[e] = ap; ap += cp[e]; }
    om[16] = am; op[16] = ap;
  }
  __syncthreads();
  if (tid < 17){ off_m[tid] = om[tid]; off_p[tid] = op[tid]; }
  if (tid < 16){ cm[tid] = om[tid]; cp[tid] = op[tid]; }
  __syncthreads();
  for (int p = tid; p < NPAIR; p += 256){
    const int pm = atomicAdd(&cm[mlp_arr[p]], 1);  mlp_list[pm]  = p;
    const int pp = atomicAdd(&cp[post_arr[p]], 1); post_list[pp] = p;
  }
}

// ---------------- LN + act over pre_lin rows (in place) ----------------
__global__ __launch_bounds__(256) void ln_act_pre_kernel(
    float* __restrict__ buf, const float* __restrict__ g, const float* __restrict__ be)
{
  const int bid = blockIdx.x;        // e*256 + t
  const int e = bid >> 8;
  const int tid = threadIdx.x;
  float* row = buf + (long)bid * DD;
  const float x1 = row[tid], x2 = row[tid+256];
  __shared__ float s1[256], s2[256];
  s1[tid] = x1 + x2; s2[tid] = x1*x1 + x2*x2;
  __syncthreads();
  for (int off = 128; off > 0; off >>= 1){
    if (tid < off){ s1[tid] += s1[tid+off]; s2[tid] += s2[tid+off]; }
    __syncthreads();
  }
  const float mu  = s1[0] * (1.0f/512.0f);
  const float var = s2[0] * (1.0f/512.0f) - mu*mu;
  const float inv = 1.0f / sqrtf(var + 1e-5f);
  const int a = e & 3;
  const float y1 = (x1 - mu) * inv * g[e*DD + tid]       + be[e*DD + tid];
  const float y2 = (x2 - mu) * inv * g[e*DD + tid + 256] + be[e*DD + tid + 256];
  row[tid]     = act_apply(a, y1);
  row[tid+256] = act_apply(a, y2);
}

// ---------------- final: per token, optional LN per pair + weighted sum ----------------
__global__ __launch_bounds__(256) void final_kernel(
    const float* __restrict__ post_lin, const float* __restrict__ w_arr,
    const int* __restrict__ post_arr,
    const float* __restrict__ pg, const float* __restrict__ pbe,
    float* __restrict__ out)
{
  const int t = blockIdx.x, tid = threadIdx.x;
  float a1 = 0.f, a2 = 0.f;
  __shared__ float s1[256], s2[256];
  for (int k = 0; k < TOPK_N; ++k){
    const int p = t*TOPK_N + k;
    const float wgt = w_arr[p];      // uniform across block
    if (wgt == 0.0f) continue;
    const float* row = post_lin + (long)p*DD;
    float z1 = row[tid], z2 = row[tid+256];
    const int e = post_arr[p];
    if ((e & 1) == 0){
      s1[tid] = z1 + z2; s2[tid] = z1*z1 + z2*z2;
      __syncthreads();
      for (int off = 128; off > 0; off >>= 1){
        if (tid < off){ s1[tid] += s1[tid+off]; s2[tid] += s2[tid+off]; }
        __syncthreads();
      }
      const float mu  = s1[0] * (1.0f/512.0f);
      const float var = s2[0] * (1.0f/512.0f) - mu*mu;
      const float inv = 1.0f / sqrtf(var + 1e-5f);
      z1 = (z1 - mu)*inv*pg[e*DD + tid]       + pbe[e*DD + tid];
      z2 = (z2 - mu)*inv*pg[e*DD + tid + 256] + pbe[e*DD + tid + 256];
      __syncthreads();
    }
    a1 = fmaf(wgt, z1, a1);
    a2 = fmaf(wgt, z2, a2);
  }
  out[(long)t*DD + tid]       = a1;
  out[(long)t*DD + tid + 256] = a2;
}

// ---------------- host launch ----------------
extern "C" void kernel_launch(void* const* d_in, const int* in_sizes, int n_in,
                              void* d_out, int out_size, void* d_ws, size_t ws_size,
                              hipStream_t stream)
{
  const float* x     = (const float*)d_in[0];
  const float* r_w1  = (const float*)d_in[1];
  const float* r_b1  = (const float*)d_in[2];
  const float* r_w2  = (const float*)d_in[3];
  const float* r_b2  = (const float*)d_in[4];
  const float* r_w3  = (const float*)d_in[5];
  const float* r_b3  = (const float*)d_in[6];
  const float* temp  = (const float*)d_in[7];
  const float* pre_w = (const float*)d_in[8];
  const float* pre_b = (const float*)d_in[9];
  const float* pre_g = (const float*)d_in[10];
  const float* pre_be= (const float*)d_in[11];
  const float* mlp_w1= (const float*)d_in[12];
  const float* mlp_b1= (const float*)d_in[13];
  const float* mlp_w2= (const float*)d_in[14];
  const float* mlp_b2= (const float*)d_in[15];
  const float* post_w= (const float*)d_in[16];
  const float* post_b= (const float*)d_in[17];
  const float* post_g= (const float*)d_in[18];
  const float* post_be=(const float*)d_in[19];

  float* ws = (float*)d_ws;
  float* h1      = ws + OFF_H1;
  float* h2      = ws + OFF_H2;
  float* scores  = ws + OFF_SCORES;
  float* pre_lin = ws + OFF_PRE;
  float* ybuf    = ws + OFF_Y;
  float* mlp_out = ws + OFF_MLPOUT;
  float* post_lin= ws + OFF_POSTLIN;
  float* w_arr   = ws + OFF_W;
  int*   wsi     = (int*)(ws + OFF_INT);
  int* pre_arr   = wsi + I_PRE;
  int* mlp_arr   = wsi + I_MLP;
  int* post_arr  = wsi + I_POST;
  int* mlp_list  = wsi + I_MLPLIST;
  int* post_list = wsi + I_POSTLIST;
  int* off_m     = wsi + I_OFFM;
  int* off_p     = wsi + I_OFFP;

  const dim3 blk(256);

  // ---- router (fp32, exact for stable top-k) ----
  init_bias_kernel<<<dim3(128), blk, 0, stream>>>(h1, r_b1, 512, 256L*512);
  gemm_dense_splitk_kernel<<<dim3(8, 4*4), blk, 0, stream>>>(
      x, DD, r_w1, DD, h1, DD, 512, 128, 4);
  act_dense_kernel<<<dim3(128), blk, 0, stream>>>(h1, 256L*512/4, 0);
  init_bias_kernel<<<dim3(64), blk, 0, stream>>>(h2, r_b2, 256, 256L*256);
  gemm_dense_splitk_kernel<<<dim3(4, 4*4), blk, 0, stream>>>(
      h1, DD, r_w2, 256, h2, 256, 512, 128, 4);
  act_dense_kernel<<<dim3(64), blk, 0, stream>>>(h2, 256L*256/4, 0);
  init_bias_kernel<<<dim3(1024), blk, 0, stream>>>(scores, r_b3, 4096, 256L*4096);
  gemm_dense_splitk_kernel<<<dim3(64, 4*2), blk, 0, stream>>>(
      h2, 256, r_w3, 4096, scores, 4096, 256, 128, 2);
  router_topk_kernel<<<dim3(TOKENS), blk, 0, stream>>>(
      scores, temp, w_arr, pre_arr, mlp_arr, post_arr);
  bucket_kernel<<<dim3(1), blk, 0, stream>>>(
      mlp_arr, post_arr, mlp_list, post_list, off_m, off_p);

  // ---- pre experts (MFMA): pre_lin = x @ pre_w[e] + pre_b[e], then LN+act ----
  mfma_pre_kernel<<<dim3(8, 4, 16), blk, 0, stream>>>(x, pre_w, pre_b, pre_lin);
  ln_act_pre_kernel<<<dim3(16*TOKENS), blk, 0, stream>>>(pre_lin, pre_g, pre_be);

  // ---- grouped mlp1 (MFMA): ybuf = act(xin @ w1[:, :he] + b1) ----
  mfma_grp1_kernel<<<dim3(40, 6, 16), blk, 0, stream>>>(
      pre_lin, mlp_w1, mlp_b1, mlp_list, off_m, pre_arr, ybuf);

  // ---- grouped mlp2 (MFMA): mlp_out[p] = ybuf @ w2[:he,:] + b2 ----
  mfma_grp2_kernel<<<dim3(8, 6, 16), blk, 0, stream>>>(
      ybuf, mlp_w2, mlp_b2, mlp_list, off_m, mlp_out);

  // ---- grouped post (MFMA): post_lin[p] = mlp_out[p] @ post_w + post_b ----
  mfma_post_kernel<<<dim3(8, 6, 16), blk, 0, stream>>>(
      mlp_out, post_w, post_b, post_list, off_p, post_lin);

  // ---- final ----
  final_kernel<<<dim3(TOKENS), blk, 0, stream>>>(
      post_lin, w_arr, post_arr, post_g, post_be, (float*)d_out);

  (void)in_sizes; (void)n_in; (void)out_size; (void)ws_size;
}